// Round 1
// baseline (3761.930 us; speedup 1.0000x reference)
//
#include <hip/hip_runtime.h>
#include <cstdint>
#include <cstddef>

typedef __bf16 bf16;
typedef __attribute__((ext_vector_type(8))) __bf16 bf16x8;
typedef __attribute__((ext_vector_type(4))) float f32x4;

constexpr int kV = 32000, kE = 1024, kL = 6, kH = 16, kB = 4, kT = 1024;
constexpr int kHS = 64, kFF = 4096;
constexpr int kM = kB * kT;              // 4096 token rows
constexpr float kScale = 0.03125f;       // E^-0.5

typedef __attribute__((address_space(1))) void gv_t;
typedef __attribute__((address_space(3))) void lv_t;

__device__ inline void gload_lds16(const void* g, void* l) {
  __builtin_amdgcn_global_load_lds((gv_t*)g, (lv_t*)l, 16, 0, 0);
}

enum { EPI_BF16 = 0, EPI_BF16_BIAS_RELU = 1, EPI_F32 = 2, EPI_F32_RES = 3, EPI_F32_BIAS = 4 };

// ---------------- GEMM: C[M,N] = A[M,K] @ B'[N,K]^T  (both bf16, row-major in K)
template <int BM, int BN, int WM, int WN, int EPI, bool CAUSAL>
__global__ __launch_bounds__((BM / WM) * (BN / WN) * 64) void gemm_k(
    const bf16* __restrict__ Ag, const bf16* __restrict__ Bg, void* Cg,
    const float* __restrict__ bias, const float* resid, int K, long lda, long ldb,
    long ldc, long sA1, long sA2, long sB1, long sB2, long sC1, long sC2, int zdiv) {
  constexpr int BK = 32;
  constexpr int NWM = BM / WM, NWN = BN / WN, NW = NWM * NWN, THREADS = NW * 64;
  constexpr int MI = WM / 16, NI = WN / 16;
  constexpr int A_CH = (BM * BK * 2) / (THREADS * 16);
  constexpr int B_CH = (BN * BK * 2) / (THREADS * 16);
  static_assert(A_CH >= 1 && B_CH >= 1, "staging chunks");
  __shared__ bf16 As[BM * BK];
  __shared__ bf16 Bs[BN * BK];
  const int tid = threadIdx.x, lane = tid & 63;
  const int bx = blockIdx.x, by = blockIdx.y, z = blockIdx.z;
  const long tm = (long)by * BM, tn = (long)bx * BN;
  if (CAUSAL && tn > tm + (BM - 1)) return;  // fully-masked tile
  const int zq = z / zdiv, zr = z % zdiv;
  Ag += (long)zq * sA1 + (long)zr * sA2;
  Bg += (long)zq * sB1 + (long)zr * sB2;
  const long cbase = (long)zq * sC1 + (long)zr * sC2;
  const int w = tid >> 6;
  const int wr = w / NWN, wc = w % NWN;
  const int wm0 = wr * WM, wn0 = wc * WN;
  const int lr = lane & 15, kg = lane >> 4;
  f32x4 acc[MI][NI] = {};

  for (int k0 = 0; k0 < K; k0 += BK) {
#pragma unroll
    for (int i = 0; i < A_CH; i++) {
      int qq = i * THREADS + tid;
      gload_lds16(Ag + (tm + (qq >> 2)) * lda + k0 + (qq & 3) * 8,
                  (char*)As + (i * THREADS + (tid & ~63)) * 16);
    }
#pragma unroll
    for (int i = 0; i < B_CH; i++) {
      int qq = i * THREADS + tid;
      gload_lds16(Bg + (tn + (qq >> 2)) * ldb + k0 + (qq & 3) * 8,
                  (char*)Bs + (i * THREADS + (tid & ~63)) * 16);
    }
    __syncthreads();  // compiler drains vmcnt before barrier
    bf16x8 af[MI], bfr[NI];
#pragma unroll
    for (int mi = 0; mi < MI; mi++)
      af[mi] = *(const bf16x8*)&As[(wm0 + mi * 16 + lr) * BK + kg * 8];
#pragma unroll
    for (int ni = 0; ni < NI; ni++)
      bfr[ni] = *(const bf16x8*)&Bs[(wn0 + ni * 16 + lr) * BK + kg * 8];
#pragma unroll
    for (int mi = 0; mi < MI; mi++)
#pragma unroll
      for (int ni = 0; ni < NI; ni++)
        acc[mi][ni] =
            __builtin_amdgcn_mfma_f32_16x16x32_bf16(af[mi], bfr[ni], acc[mi][ni], 0, 0, 0);
    __syncthreads();
  }

#pragma unroll
  for (int mi = 0; mi < MI; mi++) {
#pragma unroll
    for (int ni = 0; ni < NI; ni++) {
      const long r0 = tm + wm0 + mi * 16 + kg * 4;
      const long cc = tn + wn0 + ni * 16 + lr;
      float bi = 0.f;
      if constexpr (EPI == EPI_BF16_BIAS_RELU || EPI == EPI_F32_BIAS) bi = bias[cc];
      if constexpr (EPI == EPI_F32_RES) bi = bias ? bias[cc] : 0.f;
#pragma unroll
      for (int j = 0; j < 4; j++) {
        long off = cbase + (r0 + j) * ldc + cc;
        float val = acc[mi][ni][j];
        if constexpr (EPI == EPI_BF16)
          ((bf16*)Cg)[off] = (bf16)val;
        else if constexpr (EPI == EPI_BF16_BIAS_RELU)
          ((bf16*)Cg)[off] = (bf16)fmaxf(val + bi, 0.f);
        else if constexpr (EPI == EPI_F32)
          ((float*)Cg)[off] = val;
        else if constexpr (EPI == EPI_F32_RES)
          ((float*)Cg)[off] = resid[off] + val + bi;
        else
          ((float*)Cg)[off] = val + bi;
      }
    }
  }
}

// ---------------- transpose + f32->bf16 convert: in [K,N] f32 -> out [N,K] bf16, batched
__global__ void tcvt_k(const float* __restrict__ in, bf16* __restrict__ out, int K, int N) {
  __shared__ float t[32][33];
  long z = blockIdx.z;
  in += z * (long)K * N;
  out += z * (long)K * N;
  int n0 = blockIdx.x * 32, k0 = blockIdx.y * 32;
  int tx = threadIdx.x, ty = threadIdx.y;
#pragma unroll
  for (int i = 0; i < 32; i += 8) t[ty + i][tx] = in[(long)(k0 + ty + i) * N + n0 + tx];
  __syncthreads();
#pragma unroll
  for (int i = 0; i < 32; i += 8)
    out[(long)(n0 + ty + i) * K + k0 + tx] = (bf16)t[tx][ty + i];
}

// ---------------- embedding: x[b,t,:] = tok_emb[tok] + pos_emb[t]
__global__ void embed_k(const int* __restrict__ toks, const float* __restrict__ te,
                        const float* __restrict__ pe, float* __restrict__ x) {
  int row = blockIdx.x, tid = threadIdx.x;
  int t = row & (kT - 1);
  long tok = toks[row];
  float4 a = ((const float4*)(te + tok * kE))[tid];
  float4 p = ((const float4*)(pe + (long)t * kE))[tid];
  float4 r{a.x + p.x, a.y + p.y, a.z + p.z, a.w + p.w};
  ((float4*)(x + (long)row * kE))[tid] = r;
}

// ---------------- LayerNorm (f32 in) -> bf16 out
__global__ void ln_k(const float* __restrict__ x, const float* __restrict__ g,
                     const float* __restrict__ b, bf16* __restrict__ h) {
  int row = blockIdx.x, tid = threadIdx.x, lane = tid & 63, w = tid >> 6;
  const float4 v = ((const float4*)(x + (long)row * kE))[tid];
  float s = v.x + v.y + v.z + v.w;
  float ss = v.x * v.x + v.y * v.y + v.z * v.z + v.w * v.w;
#pragma unroll
  for (int o = 32; o; o >>= 1) {
    s += __shfl_xor(s, o);
    ss += __shfl_xor(ss, o);
  }
  __shared__ float r1[4], r2[4];
  if (lane == 0) { r1[w] = s; r2[w] = ss; }
  __syncthreads();
  s = r1[0] + r1[1] + r1[2] + r1[3];
  ss = r2[0] + r2[1] + r2[2] + r2[3];
  float mean = s * (1.f / kE);
  float var = ss * (1.f / kE) - mean * mean;
  float rs = rsqrtf(var + 1e-5f);
  float4 gg = ((const float4*)g)[tid];
  float4 bb = ((const float4*)b)[tid];
  union { bf16 o[4]; uint2 u; } pk;
  pk.o[0] = (bf16)((v.x - mean) * rs * gg.x + bb.x);
  pk.o[1] = (bf16)((v.y - mean) * rs * gg.y + bb.y);
  pk.o[2] = (bf16)((v.z - mean) * rs * gg.z + bb.z);
  pk.o[3] = (bf16)((v.w - mean) * rs * gg.w + bb.w);
  ((uint2*)(h + (long)row * kE))[tid] = pk.u;
}

// ---------------- causal softmax row: scores f32 [row, T] -> P bf16 (masked = 0)
__global__ void softmax_k(const float* __restrict__ S, bf16* __restrict__ P) {
  long row = blockIdx.x;
  int tid = threadIdx.x, lane = tid & 63, w = tid >> 6;
  int qi = (int)(row & (kT - 1));
  const float* s = S + row * kT;
  float xv[4];
  float mx = -3e38f;
#pragma unroll
  for (int i = 0; i < 4; i++) {
    int j = tid + i * 256;
    float val = (j <= qi) ? s[j] : -3e38f;
    xv[i] = val;
    mx = fmaxf(mx, val);
  }
#pragma unroll
  for (int o = 32; o; o >>= 1) mx = fmaxf(mx, __shfl_xor(mx, o));
  __shared__ float rm[4], rsum[4];
  if (lane == 0) rm[w] = mx;
  __syncthreads();
  mx = fmaxf(fmaxf(rm[0], rm[1]), fmaxf(rm[2], rm[3]));
  float e[4], sum = 0.f;
#pragma unroll
  for (int i = 0; i < 4; i++) {
    int j = tid + i * 256;
    e[i] = (j <= qi) ? __expf((xv[i] - mx) * kScale) : 0.f;
    sum += e[i];
  }
#pragma unroll
  for (int o = 32; o; o >>= 1) sum += __shfl_xor(sum, o);
  if (lane == 0) rsum[w] = sum;
  __syncthreads();
  sum = rsum[0] + rsum[1] + rsum[2] + rsum[3];
  float inv = 1.f / sum;
  bf16* p = P + row * kT;
#pragma unroll
  for (int i = 0; i < 4; i++) {
    int j = tid + i * 256;
    p[j] = (bf16)(e[i] * inv);
  }
}

// ---------------- v [B,T,H,HS] -> vT [B,H,HS,T]   (bf16)
__global__ void vtrans_k(const bf16* __restrict__ v, bf16* __restrict__ vt) {
  __shared__ bf16 t[32][33];
  int z = blockIdx.z;
  int b = z >> 4, h = z & 15;
  int t0 = blockIdx.x * 32, s0 = blockIdx.y * 32;
  int tx = threadIdx.x, ty = threadIdx.y;
#pragma unroll
  for (int i = 0; i < 32; i += 8)
    t[ty + i][tx] = v[((long)b * kT + t0 + ty + i) * kE + h * kHS + s0 + tx];
  __syncthreads();
#pragma unroll
  for (int i = 0; i < 32; i += 8)
    vt[(((long)b * kH + h) * kHS + s0 + ty + i) * kT + t0 + tx] = t[tx][ty + i];
}

// ---------------- f32 -> bf16 cast
__global__ void cast_k(const float* __restrict__ x, bf16* __restrict__ o) {
  long i = (long)blockIdx.x * 256 + threadIdx.x;
  float4 v = ((const float4*)x)[i];
  union { bf16 b[4]; uint2 u; } pk;
  pk.b[0] = (bf16)v.x;
  pk.b[1] = (bf16)v.y;
  pk.b[2] = (bf16)v.z;
  pk.b[3] = (bf16)v.w;
  ((uint2*)o)[i] = pk.u;
}

extern "C" void kernel_launch(void* const* d_in, const int* in_sizes, int n_in,
                              void* d_out, int out_size, void* d_ws, size_t ws_size,
                              hipStream_t stream) {
  const int* toks = (const int*)d_in[0];
  const float* te = (const float*)d_in[1];
  const float* pe = (const float*)d_in[2];
  const float* Wq = (const float*)d_in[3];
  const float* Wk = (const float*)d_in[4];
  const float* Wv = (const float*)d_in[5];
  const float* Wo = (const float*)d_in[6];
  const float* g1 = (const float*)d_in[7];
  const float* be1 = (const float*)d_in[8];
  const float* W1 = (const float*)d_in[9];
  const float* bb1 = (const float*)d_in[10];
  const float* W2 = (const float*)d_in[11];
  const float* bb2 = (const float*)d_in[12];
  const float* g2 = (const float*)d_in[13];
  const float* be2 = (const float*)d_in[14];
  const float* lmw = (const float*)d_in[15];
  const float* lmb = (const float*)d_in[16];

  char* ws = (char*)d_ws;
  size_t off = 0;
  auto alloc = [&](size_t bytes) -> char* {
    char* p = ws + off;
    off += (bytes + 255) & ~(size_t)255;
    return p;
  };
  bf16* WqT = (bf16*)alloc((size_t)kL * kE * kE * 2);
  bf16* WkT = (bf16*)alloc((size_t)kL * kE * kE * 2);
  bf16* WvT = (bf16*)alloc((size_t)kL * kE * kE * 2);
  bf16* WoT = (bf16*)alloc((size_t)kL * kE * kE * 2);
  bf16* W1T = (bf16*)alloc((size_t)kL * kE * kFF * 2);
  bf16* W2T = (bf16*)alloc((size_t)kL * kE * kFF * 2);
  bf16* lmT = (bf16*)alloc((size_t)kV * kE * 2);
  float* x = (float*)alloc((size_t)kM * kE * 4);
  bf16* h = (bf16*)alloc((size_t)kM * kE * 2);
  bf16* q = (bf16*)alloc((size_t)kM * kE * 2);
  bf16* kk = (bf16*)alloc((size_t)kM * kE * 2);
  bf16* vv = (bf16*)alloc((size_t)kM * kE * 2);
  bf16* at = (bf16*)alloc((size_t)kM * kE * 2);

  // d_out doubles as scratch; LM head fully overwrites it at the end.
  float* sc = (float*)d_out;                                      // [B,H,T,T] f32 (268.4 MB)
  bf16* P = (bf16*)((char*)d_out + (size_t)kB * kH * kT * kT * 4);  // [B,H,T,T] bf16 (134.2 MB)
  bf16* mid = (bf16*)((char*)d_out + 402653184ull);               // [M,FF] bf16 (33.6 MB)
  bf16* vt = (bf16*)((char*)d_out + 436207616ull);                // [B,H,HS,T] bf16 (8.4 MB)

  dim3 tb(32, 8);
  tcvt_k<<<dim3(kE / 32, kE / 32, kL), tb, 0, stream>>>(Wq, WqT, kE, kE);
  tcvt_k<<<dim3(kE / 32, kE / 32, kL), tb, 0, stream>>>(Wk, WkT, kE, kE);
  tcvt_k<<<dim3(kE / 32, kE / 32, kL), tb, 0, stream>>>(Wv, WvT, kE, kE);
  tcvt_k<<<dim3(kE / 32, kE / 32, kL), tb, 0, stream>>>(Wo, WoT, kE, kE);
  tcvt_k<<<dim3(kFF / 32, kE / 32, kL), tb, 0, stream>>>(W1, W1T, kE, kFF);
  tcvt_k<<<dim3(kE / 32, kFF / 32, kL), tb, 0, stream>>>(W2, W2T, kFF, kE);
  tcvt_k<<<dim3(kV / 32, kE / 32, 1), tb, 0, stream>>>(lmw, lmT, kE, kV);

  embed_k<<<kM, 256, 0, stream>>>(toks, te, pe, x);

  for (int l = 0; l < kL; l++) {
    ln_k<<<kM, 256, 0, stream>>>(x, g1 + l * kE, be1 + l * kE, h);
    gemm_k<128, 128, 64, 64, EPI_BF16, false><<<dim3(kE / 128, kM / 128, 1), 256, 0, stream>>>(
        h, WqT + (size_t)l * kE * kE, q, nullptr, nullptr, kE, kE, kE, kE, 0, 0, 0, 0, 0, 0, 1);
    gemm_k<128, 128, 64, 64, EPI_BF16, false><<<dim3(kE / 128, kM / 128, 1), 256, 0, stream>>>(
        h, WkT + (size_t)l * kE * kE, kk, nullptr, nullptr, kE, kE, kE, kE, 0, 0, 0, 0, 0, 0, 1);
    gemm_k<128, 128, 64, 64, EPI_BF16, false><<<dim3(kE / 128, kM / 128, 1), 256, 0, stream>>>(
        h, WvT + (size_t)l * kE * kE, vv, nullptr, nullptr, kE, kE, kE, kE, 0, 0, 0, 0, 0, 0, 1);
    // scores = q @ k^T  (per b,h; causal tile skip)
    gemm_k<128, 128, 64, 64, EPI_F32, true><<<dim3(kT / 128, kT / 128, kB * kH), 256, 0, stream>>>(
        q, kk, sc, nullptr, nullptr, kHS, kE, kE, kT, (long)kT * kE, kHS, (long)kT * kE, kHS,
        (long)kH * kT * kT, (long)kT * kT, kH);
    softmax_k<<<kB * kH * kT, 256, 0, stream>>>(sc, P);
    vtrans_k<<<dim3(kT / 32, kHS / 32, kB * kH), tb, 0, stream>>>(vv, vt);
    // attn = P @ v
    gemm_k<128, 64, 32, 64, EPI_BF16, false><<<dim3(kHS / 64, kT / 128, kB * kH), 256, 0, stream>>>(
        P, vt, at, nullptr, nullptr, kT, kT, kT, kE, (long)kH * kT * kT, (long)kT * kT,
        (long)kH * kHS * kT, (long)kHS * kT, (long)kT * kE, kHS, kH);
    // x += attn @ Wo
    gemm_k<128, 128, 64, 64, EPI_F32_RES, false><<<dim3(kE / 128, kM / 128, 1), 256, 0, stream>>>(
        at, WoT + (size_t)l * kE * kE, x, nullptr, x, kE, kE, kE, kE, 0, 0, 0, 0, 0, 0, 1);
    ln_k<<<kM, 256, 0, stream>>>(x, g2 + l * kE, be2 + l * kE, h);
    // mid = relu(h @ W1 + b1)
    gemm_k<128, 128, 64, 64, EPI_BF16_BIAS_RELU, false>
        <<<dim3(kFF / 128, kM / 128, 1), 256, 0, stream>>>(
            h, W1T + (size_t)l * (size_t)kFF * kE, mid, bb1 + l * kFF, nullptr, kE, kE, kE, kFF,
            0, 0, 0, 0, 0, 0, 1);
    // x += mid @ W2 + b2
    gemm_k<128, 128, 64, 64, EPI_F32_RES, false><<<dim3(kE / 128, kM / 128, 1), 256, 0, stream>>>(
        mid, W2T + (size_t)l * (size_t)kE * kFF, x, bb2 + l * kE, x, kFF, kFF, kFF, kE, 0, 0, 0,
        0, 0, 0, 1);
  }
  cast_k<<<kM * kE / 1024, 256, 0, stream>>>(x, h);
  // logits = x @ lmh_w + lmh_b
  gemm_k<128, 128, 64, 64, EPI_F32_BIAS, false><<<dim3(kV / 128, kM / 128, 1), 256, 0, stream>>>(
      h, lmT, d_out, lmb, nullptr, kE, kE, kE, kV, 0, 0, 0, 0, 0, 0, 1);
}

// Round 2
// 3295.626 us; speedup vs baseline: 1.1415x; 1.1415x over previous
//
#include <hip/hip_runtime.h>
#include <cstdint>
#include <cstddef>

typedef __bf16 bf16;
typedef __attribute__((ext_vector_type(8))) __bf16 bf16x8;
typedef __attribute__((ext_vector_type(4))) float f32x4;

constexpr int kV = 32000, kE = 1024, kL = 6, kH = 16, kB = 4, kT = 1024;
constexpr int kHS = 64, kFF = 4096;
constexpr int kM = kB * kT;              // 4096 token rows
constexpr float kScale = 0.03125f;       // E^-0.5

typedef __attribute__((address_space(1))) void gv_t;
typedef __attribute__((address_space(3))) void lv_t;

__device__ inline void gload_lds16(const void* g, void* l) {
  __builtin_amdgcn_global_load_lds((gv_t*)g, (lv_t*)l, 16, 0, 0);
}

enum { EPI_BF16 = 0, EPI_BF16_BIAS_RELU = 1, EPI_F32 = 2, EPI_F32_RES = 3, EPI_F32_BIAS = 4 };

// ---------------- GEMM: C[M,N] = A[M,K] @ B'[N,K]^T  (both bf16, row-major in K)
// 2-phase pipeline (T3 minimum recipe): STAGE(t+1) issued BEFORE ds_read+MFMA(t),
// double-buffered LDS, single drain+barrier per K-tile.
// XCD-aware bijective swizzle (T1/m204) when gridDim.z==1, column-major logical
// decomposition so the blocks sharing one B-panel are consecutive on an XCD.
template <int BM, int BN, int WM, int WN, int EPI, bool CAUSAL>
__global__ __launch_bounds__((BM / WM) * (BN / WN) * 64) void gemm_k(
    const bf16* __restrict__ Ag, const bf16* __restrict__ Bg, void* Cg,
    const float* __restrict__ bias, const float* resid, int K, long lda, long ldb,
    long ldc, long sA1, long sA2, long sB1, long sB2, long sC1, long sC2, int zdiv) {
  constexpr int BK = 32;
  constexpr int NWM = BM / WM, NWN = BN / WN, NW = NWM * NWN, THREADS = NW * 64;
  constexpr int MI = WM / 16, NI = WN / 16;
  constexpr int A_CH = (BM * BK * 2) / (THREADS * 16);
  constexpr int B_CH = (BN * BK * 2) / (THREADS * 16);
  static_assert(A_CH >= 1 && B_CH >= 1, "staging chunks");
  __shared__ bf16 As[2][BM * BK];
  __shared__ bf16 Bs[2][BN * BK];
  const int tid = threadIdx.x, lane = tid & 63;
  int bx = blockIdx.x, by = blockIdx.y;
  const int z = blockIdx.z;
  if (gridDim.z == 1) {  // XCD swizzle (bijective, m204)
    int gx = gridDim.x, gy = gridDim.y;
    int nxy = gx * gy;
    int orig = by * gx + bx;
    int q = nxy >> 3, r = nxy & 7, xcd = orig & 7, idx = orig >> 3;
    int logical = (xcd < r ? xcd * (q + 1) : r * (q + 1) + (xcd - r) * q) + idx;
    bx = logical / gy;  // consecutive logical ids share bx => share B panel in L2
    by = logical % gy;
  }
  const long tm = (long)by * BM, tn = (long)bx * BN;
  if (CAUSAL && tn > tm + (BM - 1)) return;  // fully-masked tile
  const int zq = z / zdiv, zr = z % zdiv;
  Ag += (long)zq * sA1 + (long)zr * sA2;
  Bg += (long)zq * sB1 + (long)zr * sB2;
  const long cbase = (long)zq * sC1 + (long)zr * sC2;
  const int w = tid >> 6;
  const int wr = w / NWN, wc = w % NWN;
  const int wm0 = wr * WM, wn0 = wc * WN;
  const int lr = lane & 15, kg = lane >> 4;
  f32x4 acc[MI][NI] = {};

  auto stage = [&](int buf, int k0) {
#pragma unroll
    for (int i = 0; i < A_CH; i++) {
      int qq = i * THREADS + tid;
      gload_lds16(Ag + (tm + (qq >> 2)) * lda + k0 + (qq & 3) * 8,
                  (char*)&As[buf][0] + (i * THREADS + (tid & ~63)) * 16);
    }
#pragma unroll
    for (int i = 0; i < B_CH; i++) {
      int qq = i * THREADS + tid;
      gload_lds16(Bg + (tn + (qq >> 2)) * ldb + k0 + (qq & 3) * 8,
                  (char*)&Bs[buf][0] + (i * THREADS + (tid & ~63)) * 16);
    }
  };

  const int nt = K / BK;
  stage(0, 0);
  __syncthreads();  // compiler drains vmcnt before barrier
  int cur = 0;
  for (int t = 0; t < nt; t++) {
    if (t + 1 < nt) stage(cur ^ 1, (t + 1) * BK);  // issue next-tile loads FIRST
    bf16x8 af[MI], bfr[NI];
#pragma unroll
    for (int mi = 0; mi < MI; mi++)
      af[mi] = *(const bf16x8*)&As[cur][(wm0 + mi * 16 + lr) * BK + kg * 8];
#pragma unroll
    for (int ni = 0; ni < NI; ni++)
      bfr[ni] = *(const bf16x8*)&Bs[cur][(wn0 + ni * 16 + lr) * BK + kg * 8];
#pragma unroll
    for (int mi = 0; mi < MI; mi++)
#pragma unroll
      for (int ni = 0; ni < NI; ni++)
        acc[mi][ni] =
            __builtin_amdgcn_mfma_f32_16x16x32_bf16(af[mi], bfr[ni], acc[mi][ni], 0, 0, 0);
    __syncthreads();  // drains vmcnt(0)+lgkmcnt(0): next buf staged, cur free
    cur ^= 1;
  }

#pragma unroll
  for (int mi = 0; mi < MI; mi++) {
#pragma unroll
    for (int ni = 0; ni < NI; ni++) {
      const long r0 = tm + wm0 + mi * 16 + kg * 4;
      const long cc = tn + wn0 + ni * 16 + lr;
      float bi = 0.f;
      if constexpr (EPI == EPI_BF16_BIAS_RELU || EPI == EPI_F32_BIAS) bi = bias[cc];
      if constexpr (EPI == EPI_F32_RES) bi = bias ? bias[cc] : 0.f;
#pragma unroll
      for (int j = 0; j < 4; j++) {
        long off = cbase + (r0 + j) * ldc + cc;
        float val = acc[mi][ni][j];
        if constexpr (EPI == EPI_BF16)
          ((bf16*)Cg)[off] = (bf16)val;
        else if constexpr (EPI == EPI_BF16_BIAS_RELU)
          ((bf16*)Cg)[off] = (bf16)fmaxf(val + bi, 0.f);
        else if constexpr (EPI == EPI_F32)
          ((float*)Cg)[off] = val;
        else if constexpr (EPI == EPI_F32_RES)
          ((float*)Cg)[off] = resid[off] + val + bi;
        else
          ((float*)Cg)[off] = val + bi;
      }
    }
  }
}

// ---------------- transpose + f32->bf16 convert: in [K,N] f32 -> out [N,K] bf16, batched
__global__ void tcvt_k(const float* __restrict__ in, bf16* __restrict__ out, int K, int N,
                       long in_zs, long out_zs) {
  __shared__ float t[32][33];
  long z = blockIdx.z;
  in += z * in_zs;
  out += z * out_zs;
  int n0 = blockIdx.x * 32, k0 = blockIdx.y * 32;
  int tx = threadIdx.x, ty = threadIdx.y;
#pragma unroll
  for (int i = 0; i < 32; i += 8) t[ty + i][tx] = in[(long)(k0 + ty + i) * N + n0 + tx];
  __syncthreads();
#pragma unroll
  for (int i = 0; i < 32; i += 8)
    out[(long)(n0 + ty + i) * K + k0 + tx] = (bf16)t[tx][ty + i];
}

// ---------------- embedding: x[b,t,:] = tok_emb[tok] + pos_emb[t]
__global__ void embed_k(const int* __restrict__ toks, const float* __restrict__ te,
                        const float* __restrict__ pe, float* __restrict__ x) {
  int row = blockIdx.x, tid = threadIdx.x;
  int t = row & (kT - 1);
  long tok = toks[row];
  float4 a = ((const float4*)(te + tok * kE))[tid];
  float4 p = ((const float4*)(pe + (long)t * kE))[tid];
  float4 r{a.x + p.x, a.y + p.y, a.z + p.z, a.w + p.w};
  ((float4*)(x + (long)row * kE))[tid] = r;
}

// ---------------- LayerNorm (f32 in) -> bf16 out
__global__ void ln_k(const float* __restrict__ x, const float* __restrict__ g,
                     const float* __restrict__ b, bf16* __restrict__ h) {
  int row = blockIdx.x, tid = threadIdx.x, lane = tid & 63, w = tid >> 6;
  const float4 v = ((const float4*)(x + (long)row * kE))[tid];
  float s = v.x + v.y + v.z + v.w;
  float ss = v.x * v.x + v.y * v.y + v.z * v.z + v.w * v.w;
#pragma unroll
  for (int o = 32; o; o >>= 1) {
    s += __shfl_xor(s, o);
    ss += __shfl_xor(ss, o);
  }
  __shared__ float r1[4], r2[4];
  if (lane == 0) { r1[w] = s; r2[w] = ss; }
  __syncthreads();
  s = r1[0] + r1[1] + r1[2] + r1[3];
  ss = r2[0] + r2[1] + r2[2] + r2[3];
  float mean = s * (1.f / kE);
  float var = ss * (1.f / kE) - mean * mean;
  float rs = rsqrtf(var + 1e-5f);
  float4 gg = ((const float4*)g)[tid];
  float4 bb = ((const float4*)b)[tid];
  union { bf16 o[4]; uint2 u; } pk;
  pk.o[0] = (bf16)((v.x - mean) * rs * gg.x + bb.x);
  pk.o[1] = (bf16)((v.y - mean) * rs * gg.y + bb.y);
  pk.o[2] = (bf16)((v.z - mean) * rs * gg.z + bb.z);
  pk.o[3] = (bf16)((v.w - mean) * rs * gg.w + bb.w);
  ((uint2*)(h + (long)row * kE))[tid] = pk.u;
}

// ---------------- causal softmax row: scores f32 [row, T] -> P bf16 (masked = 0)
__global__ void softmax_k(const float* __restrict__ S, bf16* __restrict__ P) {
  long row = blockIdx.x;
  int tid = threadIdx.x, lane = tid & 63, w = tid >> 6;
  int qi = (int)(row & (kT - 1));
  const float* s = S + row * kT;
  float xv[4];
  float mx = -3e38f;
#pragma unroll
  for (int i = 0; i < 4; i++) {
    int j = tid + i * 256;
    float val = (j <= qi) ? s[j] : -3e38f;
    xv[i] = val;
    mx = fmaxf(mx, val);
  }
#pragma unroll
  for (int o = 32; o; o >>= 1) mx = fmaxf(mx, __shfl_xor(mx, o));
  __shared__ float rm[4], rsum[4];
  if (lane == 0) rm[w] = mx;
  __syncthreads();
  mx = fmaxf(fmaxf(rm[0], rm[1]), fmaxf(rm[2], rm[3]));
  float e[4], sum = 0.f;
#pragma unroll
  for (int i = 0; i < 4; i++) {
    int j = tid + i * 256;
    e[i] = (j <= qi) ? __expf((xv[i] - mx) * kScale) : 0.f;
    sum += e[i];
  }
#pragma unroll
  for (int o = 32; o; o >>= 1) sum += __shfl_xor(sum, o);
  if (lane == 0) rsum[w] = sum;
  __syncthreads();
  sum = rsum[0] + rsum[1] + rsum[2] + rsum[3];
  float inv = 1.f / sum;
  bf16* p = P + row * kT;
#pragma unroll
  for (int i = 0; i < 4; i++) {
    int j = tid + i * 256;
    p[j] = (bf16)(e[i] * inv);
  }
}

// ---------------- v section of qkv [M, 3E] -> vT [B,H,HS,T]   (bf16)
__global__ void vtrans_k(const bf16* __restrict__ qkv, bf16* __restrict__ vt) {
  __shared__ bf16 t[32][33];
  int z = blockIdx.z;
  int b = z >> 4, h = z & 15;
  int t0 = blockIdx.x * 32, s0 = blockIdx.y * 32;
  int tx = threadIdx.x, ty = threadIdx.y;
#pragma unroll
  for (int i = 0; i < 32; i += 8)
    t[ty + i][tx] =
        qkv[((long)b * kT + t0 + ty + i) * (3 * kE) + 2 * kE + h * kHS + s0 + tx];
  __syncthreads();
#pragma unroll
  for (int i = 0; i < 32; i += 8)
    vt[(((long)b * kH + h) * kHS + s0 + ty + i) * kT + t0 + tx] = t[tx][ty + i];
}

// ---------------- f32 -> bf16 cast
__global__ void cast_k(const float* __restrict__ x, bf16* __restrict__ o) {
  long i = (long)blockIdx.x * 256 + threadIdx.x;
  float4 v = ((const float4*)x)[i];
  union { bf16 b[4]; uint2 u; } pk;
  pk.b[0] = (bf16)v.x;
  pk.b[1] = (bf16)v.y;
  pk.b[2] = (bf16)v.z;
  pk.b[3] = (bf16)v.w;
  ((uint2*)o)[i] = pk.u;
}

extern "C" void kernel_launch(void* const* d_in, const int* in_sizes, int n_in,
                              void* d_out, int out_size, void* d_ws, size_t ws_size,
                              hipStream_t stream) {
  const int* toks = (const int*)d_in[0];
  const float* te = (const float*)d_in[1];
  const float* pe = (const float*)d_in[2];
  const float* Wq = (const float*)d_in[3];
  const float* Wk = (const float*)d_in[4];
  const float* Wv = (const float*)d_in[5];
  const float* Wo = (const float*)d_in[6];
  const float* g1 = (const float*)d_in[7];
  const float* be1 = (const float*)d_in[8];
  const float* W1 = (const float*)d_in[9];
  const float* bb1 = (const float*)d_in[10];
  const float* W2 = (const float*)d_in[11];
  const float* bb2 = (const float*)d_in[12];
  const float* g2 = (const float*)d_in[13];
  const float* be2 = (const float*)d_in[14];
  const float* lmw = (const float*)d_in[15];
  const float* lmb = (const float*)d_in[16];

  char* ws = (char*)d_ws;
  size_t off = 0;
  auto alloc = [&](size_t bytes) -> char* {
    char* p = ws + off;
    off += (bytes + 255) & ~(size_t)255;
    return p;
  };
  bf16* WqkvT = (bf16*)alloc((size_t)kL * 3 * kE * kE * 2);  // [L][3E][E]
  bf16* WoT = (bf16*)alloc((size_t)kL * kE * kE * 2);
  bf16* W1T = (bf16*)alloc((size_t)kL * kE * kFF * 2);
  bf16* W2T = (bf16*)alloc((size_t)kL * kE * kFF * 2);
  bf16* lmT = (bf16*)alloc((size_t)kV * kE * 2);
  float* x = (float*)alloc((size_t)kM * kE * 4);
  bf16* h = (bf16*)alloc((size_t)kM * kE * 2);
  bf16* qkv = (bf16*)alloc((size_t)kM * 3 * kE * 2);  // [M][3E]
  bf16* at = (bf16*)alloc((size_t)kM * kE * 2);

  // d_out doubles as scratch; LM head fully overwrites it at the end.
  float* sc = (float*)d_out;                                        // [B,H,T,T] f32
  bf16* P = (bf16*)((char*)d_out + (size_t)kB * kH * kT * kT * 4);  // [B,H,T,T] bf16
  bf16* mid = (bf16*)((char*)d_out + 402653184ull);                 // [M,FF] bf16
  bf16* vt = (bf16*)((char*)d_out + 436207616ull);                  // [B,H,HS,T] bf16

  const long EE = (long)kE * kE;
  dim3 tb(32, 8);
  tcvt_k<<<dim3(kE / 32, kE / 32, kL), tb, 0, stream>>>(Wq, WqkvT, kE, kE, EE, 3 * EE);
  tcvt_k<<<dim3(kE / 32, kE / 32, kL), tb, 0, stream>>>(Wk, WqkvT + EE, kE, kE, EE, 3 * EE);
  tcvt_k<<<dim3(kE / 32, kE / 32, kL), tb, 0, stream>>>(Wv, WqkvT + 2 * EE, kE, kE, EE, 3 * EE);
  tcvt_k<<<dim3(kE / 32, kE / 32, kL), tb, 0, stream>>>(Wo, WoT, kE, kE, EE, EE);
  tcvt_k<<<dim3(kFF / 32, kE / 32, kL), tb, 0, stream>>>(W1, W1T, kE, kFF, 4 * EE, 4 * EE);
  tcvt_k<<<dim3(kE / 32, kFF / 32, kL), tb, 0, stream>>>(W2, W2T, kFF, kE, 4 * EE, 4 * EE);
  tcvt_k<<<dim3(kV / 32, kE / 32, 1), tb, 0, stream>>>(lmw, lmT, kE, kV, 0, 0);

  embed_k<<<kM, 256, 0, stream>>>(toks, te, pe, x);

  for (int l = 0; l < kL; l++) {
    ln_k<<<kM, 256, 0, stream>>>(x, g1 + l * kE, be1 + l * kE, h);
    // qkv = h @ [Wq|Wk|Wv]
    gemm_k<128, 128, 64, 64, EPI_BF16, false>
        <<<dim3(3 * kE / 128, kM / 128, 1), 256, 0, stream>>>(
            h, WqkvT + (size_t)l * 3 * EE, qkv, nullptr, nullptr, kE, kE, kE, 3 * kE, 0, 0, 0,
            0, 0, 0, 1);
    // scores = q @ k^T  (per b,h; causal tile skip)
    gemm_k<128, 128, 64, 64, EPI_F32, true><<<dim3(kT / 128, kT / 128, kB * kH), 256, 0, stream>>>(
        qkv, qkv + kE, sc, nullptr, nullptr, kHS, 3 * kE, 3 * kE, kT, (long)kT * 3 * kE, kHS,
        (long)kT * 3 * kE, kHS, (long)kH * kT * kT, (long)kT * kT, kH);
    softmax_k<<<kB * kH * kT, 256, 0, stream>>>(sc, P);
    vtrans_k<<<dim3(kT / 32, kHS / 32, kB * kH), tb, 0, stream>>>(qkv, vt);
    // attn = P @ v
    gemm_k<128, 64, 32, 64, EPI_BF16, false><<<dim3(kHS / 64, kT / 128, kB * kH), 256, 0, stream>>>(
        P, vt, at, nullptr, nullptr, kT, kT, kT, kE, (long)kH * kT * kT, (long)kT * kT,
        (long)kH * kHS * kT, (long)kHS * kT, (long)kT * kE, kHS, kH);
    // x += attn @ Wo
    gemm_k<128, 128, 64, 64, EPI_F32_RES, false><<<dim3(kE / 128, kM / 128, 1), 256, 0, stream>>>(
        at, WoT + (size_t)l * EE, x, nullptr, x, kE, kE, kE, kE, 0, 0, 0, 0, 0, 0, 1);
    ln_k<<<kM, 256, 0, stream>>>(x, g2 + l * kE, be2 + l * kE, h);
    // mid = relu(h @ W1 + b1)
    gemm_k<128, 128, 64, 64, EPI_BF16_BIAS_RELU, false>
        <<<dim3(kFF / 128, kM / 128, 1), 256, 0, stream>>>(
            h, W1T + (size_t)l * (size_t)kFF * kE, mid, bb1 + l * kFF, nullptr, kE, kE, kE, kFF,
            0, 0, 0, 0, 0, 0, 1);
    // x += mid @ W2 + b2
    gemm_k<128, 128, 64, 64, EPI_F32_RES, false><<<dim3(kE / 128, kM / 128, 1), 256, 0, stream>>>(
        mid, W2T + (size_t)l * (size_t)kE * kFF, x, bb2 + l * kE, x, kFF, kFF, kFF, kE, 0, 0, 0,
        0, 0, 0, 1);
  }
  cast_k<<<kM * kE / 1024, 256, 0, stream>>>(x, h);
  // logits = x @ lmh_w + lmh_b
  gemm_k<128, 128, 64, 64, EPI_F32_BIAS, false><<<dim3(kV / 128, kM / 128, 1), 256, 0, stream>>>(
      h, lmT, d_out, lmb, nullptr, kE, kE, kE, kV, 0, 0, 0, 0, 0, 0, 1);
}

// Round 3
// 3057.315 us; speedup vs baseline: 1.2305x; 1.0779x over previous
//
#include <hip/hip_runtime.h>
#include <cstdint>
#include <cstddef>

typedef __bf16 bf16;
typedef __attribute__((ext_vector_type(8))) __bf16 bf16x8;
typedef __attribute__((ext_vector_type(4))) float f32x4;

constexpr int kV = 32000, kE = 1024, kL = 6, kH = 16, kB = 4, kT = 1024;
constexpr int kHS = 64, kFF = 4096;
constexpr int kM = kB * kT;              // 4096 token rows
constexpr float kScale = 0.03125f;       // E^-0.5

typedef __attribute__((address_space(1))) void gv_t;
typedef __attribute__((address_space(3))) void lv_t;

__device__ inline void gload_lds16(const void* g, void* l) {
  __builtin_amdgcn_global_load_lds((gv_t*)g, (lv_t*)l, 16, 0, 0);
}

enum { EPI_BF16 = 0, EPI_BF16_BIAS_RELU = 1, EPI_F32 = 2, EPI_F32_RES = 3, EPI_F32_BIAS = 4 };

// ================= 256x256 deep-pipelined GEMM (T3+T4+T2+T5) =================
// C[M,N] = A[M,K] @ B'[N,K]^T, bf16 in. 8 waves (2x4), wave tile 128x64.
// K-slice ring: 4 slices x (A 256x32 + B 256x32) = 128 KiB dynamic LDS.
// Counted vmcnt(8) (2 slices in flight after wait), raw s_barrier, prefetch
// distance 3. LDS XOR swizzle slot^=((row>>1)&3) applied on BOTH the staged
// global source address and the ds_read address (gload_lds writes linearly).
template <int EPI>
__global__ __launch_bounds__(512, 2) void gemm256_k(
    const bf16* __restrict__ Ag, const bf16* __restrict__ Bg, void* Cg,
    const float* __restrict__ bias, const float* __restrict__ resid,
    int K, long lda, long ldb, long ldc) {
  extern __shared__ bf16 lds[];
  constexpr int SL = 8192;  // elems per slice per operand (256 rows x 32 k)
  bf16* As = lds;           // [4][SL]
  bf16* Bs = lds + 4 * SL;  // [4][SL]

  const int tid = threadIdx.x, lane = tid & 63, w = tid >> 6;
  int bx = blockIdx.x, by = blockIdx.y;
  {  // XCD bijective swizzle (m204), column-major logical order
    int gx = gridDim.x, gy = gridDim.y;
    int nxy = gx * gy;
    int orig = by * gx + bx;
    int q = nxy >> 3, r = nxy & 7, xcd = orig & 7, idx = orig >> 3;
    int logical = (xcd < r ? xcd * (q + 1) : r * (q + 1) + (xcd - r) * q) + idx;
    bx = logical / gy;
    by = logical % gy;
  }
  const long tm = (long)by * 256, tn = (long)bx * 256;
  const int wr = w >> 2, wc = w & 3;          // wave grid 2 x 4
  const int lr = lane & 15, kg = lane >> 4;

  // ---- staging precompute: 4 gload_lds per thread per slice.
  // physical granule p = i*512 + tid; row = p>>2, pslot = p&3,
  // logical slot = pslot ^ ((row>>1)&3)  (involution; read side uses same XOR)
  const int p0 = tid, p1 = 512 + tid;
  const int r0 = p0 >> 2, ls0 = (p0 & 3) ^ ((r0 >> 1) & 3);
  const int r1 = p1 >> 2, ls1 = (p1 & 3) ^ ((r1 >> 1) & 3);
  const bf16* a0 = Ag + (tm + r0) * lda + ls0 * 8;
  const bf16* a1 = Ag + (tm + r1) * lda + ls1 * 8;
  const bf16* b0 = Bg + (tn + r0) * ldb + ls0 * 8;
  const bf16* b1 = Bg + (tn + r1) * ldb + ls1 * 8;
  const int wb = w * 1024;  // wave-uniform LDS byte offset for instr 0

  auto stage = [&](int s) {
    const int slot = s & 3;
    const long k0 = (long)s * 32;
    char* Ab = (char*)As + slot * (SL * 2);
    char* Bb = (char*)Bs + slot * (SL * 2);
    gload_lds16(a0 + k0, Ab + wb);
    gload_lds16(a1 + k0, Ab + 8192 + wb);
    gload_lds16(b0 + k0, Bb + wb);
    gload_lds16(b1 + k0, Bb + 8192 + wb);
  };

  // ---- fragment ds_read byte offsets (slot-relative, swizzled)
  int aoff[8], boff[4];
#pragma unroll
  for (int mi = 0; mi < 8; mi++) {
    int ar = wr * 128 + mi * 16 + lr;
    aoff[mi] = ar * 64 + ((kg ^ ((ar >> 1) & 3)) << 4);
  }
#pragma unroll
  for (int ni = 0; ni < 4; ni++) {
    int br = wc * 64 + ni * 16 + lr;
    boff[ni] = br * 64 + ((kg ^ ((br >> 1) & 3)) << 4);
  }

  f32x4 acc[8][4] = {};
  stage(0);
  stage(1);
  stage(2);
  const int NS = K >> 5;
  for (int s = 0; s < NS; s++) {
    __builtin_amdgcn_sched_barrier(0);  // pin prior ds_reads/MFMAs before barrier
    if (s <= NS - 3)
      asm volatile("s_waitcnt vmcnt(8)" ::: "memory");
    else if (s == NS - 2)
      asm volatile("s_waitcnt vmcnt(4)" ::: "memory");
    else
      asm volatile("s_waitcnt vmcnt(0)" ::: "memory");
    __builtin_amdgcn_s_barrier();       // raw: no implicit vmcnt(0) drain
    __builtin_amdgcn_sched_barrier(0);
    if (s + 3 < NS) stage(s + 3);       // into slot[(s+3)&3] == slot[(s-1)&3]
    const char* Ab = (const char*)As + (s & 3) * (SL * 2);
    const char* Bb = (const char*)Bs + (s & 3) * (SL * 2);
    bf16x8 af[8], bfr[4];
#pragma unroll
    for (int mi = 0; mi < 8; mi++) af[mi] = *(const bf16x8*)(Ab + aoff[mi]);
#pragma unroll
    for (int ni = 0; ni < 4; ni++) bfr[ni] = *(const bf16x8*)(Bb + boff[ni]);
    __builtin_amdgcn_s_setprio(1);
#pragma unroll
    for (int mi = 0; mi < 8; mi++)
#pragma unroll
      for (int ni = 0; ni < 4; ni++)
        acc[mi][ni] =
            __builtin_amdgcn_mfma_f32_16x16x32_bf16(af[mi], bfr[ni], acc[mi][ni], 0, 0, 0);
    __builtin_amdgcn_s_setprio(0);
  }

#pragma unroll
  for (int mi = 0; mi < 8; mi++) {
#pragma unroll
    for (int ni = 0; ni < 4; ni++) {
      const long rr = tm + wr * 128 + mi * 16 + kg * 4;
      const long cc = tn + wc * 64 + ni * 16 + lr;
      float bi = 0.f;
      if constexpr (EPI == EPI_BF16_BIAS_RELU || EPI == EPI_F32_BIAS) bi = bias[cc];
      if constexpr (EPI == EPI_F32_RES) bi = bias ? bias[cc] : 0.f;
#pragma unroll
      for (int j = 0; j < 4; j++) {
        long off = (rr + j) * ldc + cc;
        float val = acc[mi][ni][j];
        if constexpr (EPI == EPI_BF16)
          ((bf16*)Cg)[off] = (bf16)val;
        else if constexpr (EPI == EPI_BF16_BIAS_RELU)
          ((bf16*)Cg)[off] = (bf16)fmaxf(val + bi, 0.f);
        else if constexpr (EPI == EPI_F32)
          ((float*)Cg)[off] = val;
        else if constexpr (EPI == EPI_F32_RES)
          ((float*)Cg)[off] = resid[off] + val + bi;
        else
          ((float*)Cg)[off] = val + bi;
      }
    }
  }
}

// ================= 128x128 2-phase GEMM (attention / small-N) =================
template <int BM, int BN, int WM, int WN, int EPI, bool CAUSAL>
__global__ __launch_bounds__((BM / WM) * (BN / WN) * 64) void gemm_k(
    const bf16* __restrict__ Ag, const bf16* __restrict__ Bg, void* Cg,
    const float* __restrict__ bias, const float* resid, int K, long lda, long ldb,
    long ldc, long sA1, long sA2, long sB1, long sB2, long sC1, long sC2, int zdiv) {
  constexpr int BK = 32;
  constexpr int NWM = BM / WM, NWN = BN / WN, NW = NWM * NWN, THREADS = NW * 64;
  constexpr int MI = WM / 16, NI = WN / 16;
  constexpr int A_CH = (BM * BK * 2) / (THREADS * 16);
  constexpr int B_CH = (BN * BK * 2) / (THREADS * 16);
  static_assert(A_CH >= 1 && B_CH >= 1, "staging chunks");
  __shared__ bf16 As[2][BM * BK];
  __shared__ bf16 Bs[2][BN * BK];
  const int tid = threadIdx.x, lane = tid & 63;
  int bx = blockIdx.x, by = blockIdx.y;
  const int z = blockIdx.z;
  if (gridDim.z == 1) {  // XCD swizzle (bijective, m204)
    int gx = gridDim.x, gy = gridDim.y;
    int nxy = gx * gy;
    int orig = by * gx + bx;
    int q = nxy >> 3, r = nxy & 7, xcd = orig & 7, idx = orig >> 3;
    int logical = (xcd < r ? xcd * (q + 1) : r * (q + 1) + (xcd - r) * q) + idx;
    bx = logical / gy;
    by = logical % gy;
  }
  const long tm = (long)by * BM, tn = (long)bx * BN;
  if (CAUSAL && tn > tm + (BM - 1)) return;  // fully-masked tile
  const int zq = z / zdiv, zr = z % zdiv;
  Ag += (long)zq * sA1 + (long)zr * sA2;
  Bg += (long)zq * sB1 + (long)zr * sB2;
  const long cbase = (long)zq * sC1 + (long)zr * sC2;
  const int w = tid >> 6;
  const int wr = w / NWN, wc = w % NWN;
  const int wm0 = wr * WM, wn0 = wc * WN;
  const int lr = lane & 15, kg = lane >> 4;
  f32x4 acc[MI][NI] = {};

  auto stage = [&](int buf, int k0) {
#pragma unroll
    for (int i = 0; i < A_CH; i++) {
      int qq = i * THREADS + tid;
      gload_lds16(Ag + (tm + (qq >> 2)) * lda + k0 + (qq & 3) * 8,
                  (char*)&As[buf][0] + (i * THREADS + (tid & ~63)) * 16);
    }
#pragma unroll
    for (int i = 0; i < B_CH; i++) {
      int qq = i * THREADS + tid;
      gload_lds16(Bg + (tn + (qq >> 2)) * ldb + k0 + (qq & 3) * 8,
                  (char*)&Bs[buf][0] + (i * THREADS + (tid & ~63)) * 16);
    }
  };

  const int nt = K / BK;
  stage(0, 0);
  __syncthreads();
  int cur = 0;
  for (int t = 0; t < nt; t++) {
    if (t + 1 < nt) stage(cur ^ 1, (t + 1) * BK);
    bf16x8 af[MI], bfr[NI];
#pragma unroll
    for (int mi = 0; mi < MI; mi++)
      af[mi] = *(const bf16x8*)&As[cur][(wm0 + mi * 16 + lr) * BK + kg * 8];
#pragma unroll
    for (int ni = 0; ni < NI; ni++)
      bfr[ni] = *(const bf16x8*)&Bs[cur][(wn0 + ni * 16 + lr) * BK + kg * 8];
#pragma unroll
    for (int mi = 0; mi < MI; mi++)
#pragma unroll
      for (int ni = 0; ni < NI; ni++)
        acc[mi][ni] =
            __builtin_amdgcn_mfma_f32_16x16x32_bf16(af[mi], bfr[ni], acc[mi][ni], 0, 0, 0);
    __syncthreads();
    cur ^= 1;
  }

#pragma unroll
  for (int mi = 0; mi < MI; mi++) {
#pragma unroll
    for (int ni = 0; ni < NI; ni++) {
      const long rr = tm + wm0 + mi * 16 + kg * 4;
      const long cc = tn + wn0 + ni * 16 + lr;
      float bi = 0.f;
      if constexpr (EPI == EPI_BF16_BIAS_RELU || EPI == EPI_F32_BIAS) bi = bias[cc];
      if constexpr (EPI == EPI_F32_RES) bi = bias ? bias[cc] : 0.f;
#pragma unroll
      for (int j = 0; j < 4; j++) {
        long off = cbase + (rr + j) * ldc + cc;
        float val = acc[mi][ni][j];
        if constexpr (EPI == EPI_BF16)
          ((bf16*)Cg)[off] = (bf16)val;
        else if constexpr (EPI == EPI_BF16_BIAS_RELU)
          ((bf16*)Cg)[off] = (bf16)fmaxf(val + bi, 0.f);
        else if constexpr (EPI == EPI_F32)
          ((float*)Cg)[off] = val;
        else if constexpr (EPI == EPI_F32_RES)
          ((float*)Cg)[off] = resid[off] + val + bi;
        else
          ((float*)Cg)[off] = val + bi;
      }
    }
  }
}

// ---------------- transpose + f32->bf16 convert: in [K,N] f32 -> out [N,K] bf16
__global__ void tcvt_k(const float* __restrict__ in, bf16* __restrict__ out, int K, int N,
                       long in_zs, long out_zs) {
  __shared__ float t[32][33];
  long z = blockIdx.z;
  in += z * in_zs;
  out += z * out_zs;
  int n0 = blockIdx.x * 32, k0 = blockIdx.y * 32;
  int tx = threadIdx.x, ty = threadIdx.y;
#pragma unroll
  for (int i = 0; i < 32; i += 8) t[ty + i][tx] = in[(long)(k0 + ty + i) * N + n0 + tx];
  __syncthreads();
#pragma unroll
  for (int i = 0; i < 32; i += 8)
    out[(long)(n0 + ty + i) * K + k0 + tx] = (bf16)t[tx][ty + i];
}

// ---------------- embedding
__global__ void embed_k(const int* __restrict__ toks, const float* __restrict__ te,
                        const float* __restrict__ pe, float* __restrict__ x) {
  int row = blockIdx.x, tid = threadIdx.x;
  int t = row & (kT - 1);
  long tok = toks[row];
  float4 a = ((const float4*)(te + tok * kE))[tid];
  float4 p = ((const float4*)(pe + (long)t * kE))[tid];
  float4 r{a.x + p.x, a.y + p.y, a.z + p.z, a.w + p.w};
  ((float4*)(x + (long)row * kE))[tid] = r;
}

// ---------------- LayerNorm (f32 in) -> bf16 out
__global__ void ln_k(const float* __restrict__ x, const float* __restrict__ g,
                     const float* __restrict__ b, bf16* __restrict__ h) {
  int row = blockIdx.x, tid = threadIdx.x, lane = tid & 63, w = tid >> 6;
  const float4 v = ((const float4*)(x + (long)row * kE))[tid];
  float s = v.x + v.y + v.z + v.w;
  float ss = v.x * v.x + v.y * v.y + v.z * v.z + v.w * v.w;
#pragma unroll
  for (int o = 32; o; o >>= 1) {
    s += __shfl_xor(s, o);
    ss += __shfl_xor(ss, o);
  }
  __shared__ float r1[4], r2[4];
  if (lane == 0) { r1[w] = s; r2[w] = ss; }
  __syncthreads();
  s = r1[0] + r1[1] + r1[2] + r1[3];
  ss = r2[0] + r2[1] + r2[2] + r2[3];
  float mean = s * (1.f / kE);
  float var = ss * (1.f / kE) - mean * mean;
  float rs = rsqrtf(var + 1e-5f);
  float4 gg = ((const float4*)g)[tid];
  float4 bb = ((const float4*)b)[tid];
  union { bf16 o[4]; uint2 u; } pk;
  pk.o[0] = (bf16)((v.x - mean) * rs * gg.x + bb.x);
  pk.o[1] = (bf16)((v.y - mean) * rs * gg.y + bb.y);
  pk.o[2] = (bf16)((v.z - mean) * rs * gg.z + bb.z);
  pk.o[3] = (bf16)((v.w - mean) * rs * gg.w + bb.w);
  ((uint2*)(h + (long)row * kE))[tid] = pk.u;
}

// ---------------- causal softmax row
__global__ void softmax_k(const float* __restrict__ S, bf16* __restrict__ P) {
  long row = blockIdx.x;
  int tid = threadIdx.x, lane = tid & 63, w = tid >> 6;
  int qi = (int)(row & (kT - 1));
  const float* s = S + row * kT;
  float xv[4];
  float mx = -3e38f;
#pragma unroll
  for (int i = 0; i < 4; i++) {
    int j = tid + i * 256;
    float val = (j <= qi) ? s[j] : -3e38f;
    xv[i] = val;
    mx = fmaxf(mx, val);
  }
#pragma unroll
  for (int o = 32; o; o >>= 1) mx = fmaxf(mx, __shfl_xor(mx, o));
  __shared__ float rm[4], rsum[4];
  if (lane == 0) rm[w] = mx;
  __syncthreads();
  mx = fmaxf(fmaxf(rm[0], rm[1]), fmaxf(rm[2], rm[3]));
  float e[4], sum = 0.f;
#pragma unroll
  for (int i = 0; i < 4; i++) {
    int j = tid + i * 256;
    e[i] = (j <= qi) ? __expf((xv[i] - mx) * kScale) : 0.f;
    sum += e[i];
  }
#pragma unroll
  for (int o = 32; o; o >>= 1) sum += __shfl_xor(sum, o);
  if (lane == 0) rsum[w] = sum;
  __syncthreads();
  sum = rsum[0] + rsum[1] + rsum[2] + rsum[3];
  float inv = 1.f / sum;
  bf16* p = P + row * kT;
#pragma unroll
  for (int i = 0; i < 4; i++) {
    int j = tid + i * 256;
    p[j] = (bf16)(e[i] * inv);
  }
}

// ---------------- v section of qkv [M, 3E] -> vT [B,H,HS,T]
__global__ void vtrans_k(const bf16* __restrict__ qkv, bf16* __restrict__ vt) {
  __shared__ bf16 t[32][33];
  int z = blockIdx.z;
  int b = z >> 4, h = z & 15;
  int t0 = blockIdx.x * 32, s0 = blockIdx.y * 32;
  int tx = threadIdx.x, ty = threadIdx.y;
#pragma unroll
  for (int i = 0; i < 32; i += 8)
    t[ty + i][tx] =
        qkv[((long)b * kT + t0 + ty + i) * (3 * kE) + 2 * kE + h * kHS + s0 + tx];
  __syncthreads();
#pragma unroll
  for (int i = 0; i < 32; i += 8)
    vt[(((long)b * kH + h) * kHS + s0 + ty + i) * kT + t0 + tx] = t[tx][ty + i];
}

// ---------------- f32 -> bf16 cast
__global__ void cast_k(const float* __restrict__ x, bf16* __restrict__ o) {
  long i = (long)blockIdx.x * 256 + threadIdx.x;
  float4 v = ((const float4*)x)[i];
  union { bf16 b[4]; uint2 u; } pk;
  pk.b[0] = (bf16)v.x;
  pk.b[1] = (bf16)v.y;
  pk.b[2] = (bf16)v.z;
  pk.b[3] = (bf16)v.w;
  ((uint2*)o)[i] = pk.u;
}

extern "C" void kernel_launch(void* const* d_in, const int* in_sizes, int n_in,
                              void* d_out, int out_size, void* d_ws, size_t ws_size,
                              hipStream_t stream) {
  const int* toks = (const int*)d_in[0];
  const float* te = (const float*)d_in[1];
  const float* pe = (const float*)d_in[2];
  const float* Wq = (const float*)d_in[3];
  const float* Wk = (const float*)d_in[4];
  const float* Wv = (const float*)d_in[5];
  const float* Wo = (const float*)d_in[6];
  const float* g1 = (const float*)d_in[7];
  const float* be1 = (const float*)d_in[8];
  const float* W1 = (const float*)d_in[9];
  const float* bb1 = (const float*)d_in[10];
  const float* W2 = (const float*)d_in[11];
  const float* bb2 = (const float*)d_in[12];
  const float* g2 = (const float*)d_in[13];
  const float* be2 = (const float*)d_in[14];
  const float* lmw = (const float*)d_in[15];
  const float* lmb = (const float*)d_in[16];

  // allow 128 KiB dynamic LDS on the 256^2 kernels (idempotent host calls)
  hipFuncSetAttribute(reinterpret_cast<const void*>(&gemm256_k<EPI_BF16>),
                      hipFuncAttributeMaxDynamicSharedMemorySize, 131072);
  hipFuncSetAttribute(reinterpret_cast<const void*>(&gemm256_k<EPI_BF16_BIAS_RELU>),
                      hipFuncAttributeMaxDynamicSharedMemorySize, 131072);
  hipFuncSetAttribute(reinterpret_cast<const void*>(&gemm256_k<EPI_F32_BIAS>),
                      hipFuncAttributeMaxDynamicSharedMemorySize, 131072);

  char* ws = (char*)d_ws;
  size_t off = 0;
  auto alloc = [&](size_t bytes) -> char* {
    char* p = ws + off;
    off += (bytes + 255) & ~(size_t)255;
    return p;
  };
  bf16* WqkvT = (bf16*)alloc((size_t)kL * 3 * kE * kE * 2);  // [L][3E][E]
  bf16* WoT = (bf16*)alloc((size_t)kL * kE * kE * 2);
  bf16* W1T = (bf16*)alloc((size_t)kL * kE * kFF * 2);
  bf16* W2T = (bf16*)alloc((size_t)kL * kE * kFF * 2);
  bf16* lmT = (bf16*)alloc((size_t)kV * kE * 2);
  float* x = (float*)alloc((size_t)kM * kE * 4);
  bf16* h = (bf16*)alloc((size_t)kM * kE * 2);
  bf16* qkv = (bf16*)alloc((size_t)kM * 3 * kE * 2);  // [M][3E]
  bf16* at = (bf16*)alloc((size_t)kM * kE * 2);

  // d_out doubles as scratch; LM head fully overwrites it at the end.
  float* sc = (float*)d_out;                                        // [B,H,T,T] f32
  bf16* P = (bf16*)((char*)d_out + (size_t)kB * kH * kT * kT * 4);  // [B,H,T,T] bf16
  bf16* mid = (bf16*)((char*)d_out + 402653184ull);                 // [M,FF] bf16
  bf16* vt = (bf16*)((char*)d_out + 436207616ull);                  // [B,H,HS,T] bf16

  const long EE = (long)kE * kE;
  dim3 tb(32, 8);
  tcvt_k<<<dim3(kE / 32, kE / 32, kL), tb, 0, stream>>>(Wq, WqkvT, kE, kE, EE, 3 * EE);
  tcvt_k<<<dim3(kE / 32, kE / 32, kL), tb, 0, stream>>>(Wk, WqkvT + EE, kE, kE, EE, 3 * EE);
  tcvt_k<<<dim3(kE / 32, kE / 32, kL), tb, 0, stream>>>(Wv, WqkvT + 2 * EE, kE, kE, EE, 3 * EE);
  tcvt_k<<<dim3(kE / 32, kE / 32, kL), tb, 0, stream>>>(Wo, WoT, kE, kE, EE, EE);
  tcvt_k<<<dim3(kFF / 32, kE / 32, kL), tb, 0, stream>>>(W1, W1T, kE, kFF, 4 * EE, 4 * EE);
  tcvt_k<<<dim3(kE / 32, kFF / 32, kL), tb, 0, stream>>>(W2, W2T, kFF, kE, 4 * EE, 4 * EE);
  tcvt_k<<<dim3(kV / 32, kE / 32, 1), tb, 0, stream>>>(lmw, lmT, kE, kV, 0, 0);

  embed_k<<<kM, 256, 0, stream>>>(toks, te, pe, x);

  for (int l = 0; l < kL; l++) {
    ln_k<<<kM, 256, 0, stream>>>(x, g1 + l * kE, be1 + l * kE, h);
    // qkv = h @ [Wq|Wk|Wv]   (256^2 pipelined)
    gemm256_k<EPI_BF16><<<dim3(3 * kE / 256, kM / 256), 512, 131072, stream>>>(
        h, WqkvT + (size_t)l * 3 * EE, qkv, nullptr, nullptr, kE, kE, kE, 3 * kE);
    // scores = q @ k^T  (per b,h; causal tile skip)
    gemm_k<128, 128, 64, 64, EPI_F32, true><<<dim3(kT / 128, kT / 128, kB * kH), 256, 0, stream>>>(
        qkv, qkv + kE, sc, nullptr, nullptr, kHS, 3 * kE, 3 * kE, kT, (long)kT * 3 * kE, kHS,
        (long)kT * 3 * kE, kHS, (long)kH * kT * kT, (long)kT * kT, kH);
    softmax_k<<<kB * kH * kT, 256, 0, stream>>>(sc, P);
    vtrans_k<<<dim3(kT / 32, kHS / 32, kB * kH), tb, 0, stream>>>(qkv, vt);
    // attn = P @ v
    gemm_k<128, 64, 32, 64, EPI_BF16, false><<<dim3(kHS / 64, kT / 128, kB * kH), 256, 0, stream>>>(
        P, vt, at, nullptr, nullptr, kT, kT, kT, kE, (long)kH * kT * kT, (long)kT * kT,
        (long)kH * kHS * kT, (long)kHS * kT, (long)kT * kE, kHS, kH);
    // x += attn @ Wo
    gemm_k<128, 128, 64, 64, EPI_F32_RES, false><<<dim3(kE / 128, kM / 128, 1), 256, 0, stream>>>(
        at, WoT + (size_t)l * EE, x, nullptr, x, kE, kE, kE, kE, 0, 0, 0, 0, 0, 0, 1);
    ln_k<<<kM, 256, 0, stream>>>(x, g2 + l * kE, be2 + l * kE, h);
    // mid = relu(h @ W1 + b1)   (256^2 pipelined)
    gemm256_k<EPI_BF16_BIAS_RELU><<<dim3(kFF / 256, kM / 256), 512, 131072, stream>>>(
        h, W1T + (size_t)l * (size_t)kFF * kE, mid, bb1 + l * kFF, nullptr, kE, kE, kE, kFF);
    // x += mid @ W2 + b2
    gemm_k<128, 128, 64, 64, EPI_F32_RES, false><<<dim3(kE / 128, kM / 128, 1), 256, 0, stream>>>(
        mid, W2T + (size_t)l * (size_t)kE * kFF, x, bb2 + l * kE, x, kFF, kFF, kFF, kE, 0, 0, 0,
        0, 0, 0, 1);
  }
  cast_k<<<kM * kE / 1024, 256, 0, stream>>>(x, h);
  // logits = x @ lmh_w + lmh_b   (256^2 pipelined)
  gemm256_k<EPI_F32_BIAS><<<dim3(kV / 256, kM / 256), 512, 131072, stream>>>(
      h, lmT, d_out, lmb, nullptr, kE, kE, kE, kV);
}

// Round 4
// 2428.241 us; speedup vs baseline: 1.5492x; 1.2591x over previous
//
#include <hip/hip_runtime.h>
#include <cstdint>
#include <cstddef>

typedef __bf16 bf16;
typedef __attribute__((ext_vector_type(8))) __bf16 bf16x8;
typedef __attribute__((ext_vector_type(4))) float f32x4;

constexpr int kV = 32000, kE = 1024, kL = 6, kH = 16, kB = 4, kT = 1024;
constexpr int kHS = 64, kFF = 4096;
constexpr int kM = kB * kT;              // 4096 token rows
constexpr float kScale = 0.03125f;       // E^-0.5

typedef __attribute__((address_space(1))) void gv_t;
typedef __attribute__((address_space(3))) void lv_t;

__device__ inline void gload_lds16(const void* g, void* l) {
  __builtin_amdgcn_global_load_lds((gv_t*)g, (lv_t*)l, 16, 0, 0);
}

enum { EPI_BF16 = 0, EPI_BF16_BIAS_RELU = 1, EPI_F32 = 2, EPI_F32_RES = 3, EPI_F32_BIAS = 4 };

// ================= 256x256 deep-pipelined GEMM (T3+T4+T2+T5) =================
template <int EPI>
__global__ __launch_bounds__(512, 2) void gemm256_k(
    const bf16* __restrict__ Ag, const bf16* __restrict__ Bg, void* Cg,
    const float* __restrict__ bias, const float* __restrict__ resid,
    int K, long lda, long ldb, long ldc) {
  extern __shared__ bf16 lds[];
  constexpr int SL = 8192;  // elems per slice per operand (256 rows x 32 k)
  bf16* As = lds;           // [4][SL]
  bf16* Bs = lds + 4 * SL;  // [4][SL]

  const int tid = threadIdx.x, lane = tid & 63, w = tid >> 6;
  int bx = blockIdx.x, by = blockIdx.y;
  {  // XCD bijective swizzle (m204), column-major logical order
    int gx = gridDim.x, gy = gridDim.y;
    int nxy = gx * gy;
    int orig = by * gx + bx;
    int q = nxy >> 3, r = nxy & 7, xcd = orig & 7, idx = orig >> 3;
    int logical = (xcd < r ? xcd * (q + 1) : r * (q + 1) + (xcd - r) * q) + idx;
    bx = logical / gy;
    by = logical % gy;
  }
  const long tm = (long)by * 256, tn = (long)bx * 256;
  const int wr = w >> 2, wc = w & 3;          // wave grid 2 x 4
  const int lr = lane & 15, kg = lane >> 4;

  const int p0 = tid, p1 = 512 + tid;
  const int r0 = p0 >> 2, ls0 = (p0 & 3) ^ ((r0 >> 1) & 3);
  const int r1 = p1 >> 2, ls1 = (p1 & 3) ^ ((r1 >> 1) & 3);
  const bf16* a0 = Ag + (tm + r0) * lda + ls0 * 8;
  const bf16* a1 = Ag + (tm + r1) * lda + ls1 * 8;
  const bf16* b0 = Bg + (tn + r0) * ldb + ls0 * 8;
  const bf16* b1 = Bg + (tn + r1) * ldb + ls1 * 8;
  const int wb = w * 1024;

  auto stage = [&](int s) {
    const int slot = s & 3;
    const long k0 = (long)s * 32;
    char* Ab = (char*)As + slot * (SL * 2);
    char* Bb = (char*)Bs + slot * (SL * 2);
    gload_lds16(a0 + k0, Ab + wb);
    gload_lds16(a1 + k0, Ab + 8192 + wb);
    gload_lds16(b0 + k0, Bb + wb);
    gload_lds16(b1 + k0, Bb + 8192 + wb);
  };

  int aoff[8], boff[4];
#pragma unroll
  for (int mi = 0; mi < 8; mi++) {
    int ar = wr * 128 + mi * 16 + lr;
    aoff[mi] = ar * 64 + ((kg ^ ((ar >> 1) & 3)) << 4);
  }
#pragma unroll
  for (int ni = 0; ni < 4; ni++) {
    int br = wc * 64 + ni * 16 + lr;
    boff[ni] = br * 64 + ((kg ^ ((br >> 1) & 3)) << 4);
  }

  f32x4 acc[8][4] = {};
  stage(0);
  stage(1);
  stage(2);
  const int NS = K >> 5;
  for (int s = 0; s < NS; s++) {
    __builtin_amdgcn_sched_barrier(0);
    if (s <= NS - 3)
      asm volatile("s_waitcnt vmcnt(8)" ::: "memory");
    else if (s == NS - 2)
      asm volatile("s_waitcnt vmcnt(4)" ::: "memory");
    else
      asm volatile("s_waitcnt vmcnt(0)" ::: "memory");
    __builtin_amdgcn_s_barrier();
    __builtin_amdgcn_sched_barrier(0);
    if (s + 3 < NS) stage(s + 3);
    const char* Ab = (const char*)As + (s & 3) * (SL * 2);
    const char* Bb = (const char*)Bs + (s & 3) * (SL * 2);
    bf16x8 af[8], bfr[4];
#pragma unroll
    for (int mi = 0; mi < 8; mi++) af[mi] = *(const bf16x8*)(Ab + aoff[mi]);
#pragma unroll
    for (int ni = 0; ni < 4; ni++) bfr[ni] = *(const bf16x8*)(Bb + boff[ni]);
    __builtin_amdgcn_s_setprio(1);
#pragma unroll
    for (int mi = 0; mi < 8; mi++)
#pragma unroll
      for (int ni = 0; ni < 4; ni++)
        acc[mi][ni] =
            __builtin_amdgcn_mfma_f32_16x16x32_bf16(af[mi], bfr[ni], acc[mi][ni], 0, 0, 0);
    __builtin_amdgcn_s_setprio(0);
  }

#pragma unroll
  for (int mi = 0; mi < 8; mi++) {
#pragma unroll
    for (int ni = 0; ni < 4; ni++) {
      const long rr = tm + wr * 128 + mi * 16 + kg * 4;
      const long cc = tn + wc * 64 + ni * 16 + lr;
      float bi = 0.f;
      if constexpr (EPI == EPI_BF16_BIAS_RELU || EPI == EPI_F32_BIAS) bi = bias[cc];
      if constexpr (EPI == EPI_F32_RES) bi = bias ? bias[cc] : 0.f;
#pragma unroll
      for (int j = 0; j < 4; j++) {
        long off = (rr + j) * ldc + cc;
        float val = acc[mi][ni][j];
        if constexpr (EPI == EPI_BF16)
          ((bf16*)Cg)[off] = (bf16)val;
        else if constexpr (EPI == EPI_BF16_BIAS_RELU)
          ((bf16*)Cg)[off] = (bf16)fmaxf(val + bi, 0.f);
        else if constexpr (EPI == EPI_F32)
          ((float*)Cg)[off] = val;
        else if constexpr (EPI == EPI_F32_RES)
          ((float*)Cg)[off] = resid[off] + val + bi;
        else
          ((float*)Cg)[off] = val + bi;
      }
    }
  }
}

// ================= 128x128 2-phase GEMM (small-N epilogue GEMMs) =================
template <int BM, int BN, int WM, int WN, int EPI, bool CAUSAL>
__global__ __launch_bounds__((BM / WM) * (BN / WN) * 64) void gemm_k(
    const bf16* __restrict__ Ag, const bf16* __restrict__ Bg, void* Cg,
    const float* __restrict__ bias, const float* resid, int K, long lda, long ldb,
    long ldc, long sA1, long sA2, long sB1, long sB2, long sC1, long sC2, int zdiv) {
  constexpr int BK = 32;
  constexpr int NWM = BM / WM, NWN = BN / WN, NW = NWM * NWN, THREADS = NW * 64;
  constexpr int MI = WM / 16, NI = WN / 16;
  constexpr int A_CH = (BM * BK * 2) / (THREADS * 16);
  constexpr int B_CH = (BN * BK * 2) / (THREADS * 16);
  static_assert(A_CH >= 1 && B_CH >= 1, "staging chunks");
  __shared__ bf16 As[2][BM * BK];
  __shared__ bf16 Bs[2][BN * BK];
  const int tid = threadIdx.x, lane = tid & 63;
  int bx = blockIdx.x, by = blockIdx.y;
  const int z = blockIdx.z;
  if (gridDim.z == 1) {
    int gx = gridDim.x, gy = gridDim.y;
    int nxy = gx * gy;
    int orig = by * gx + bx;
    int q = nxy >> 3, r = nxy & 7, xcd = orig & 7, idx = orig >> 3;
    int logical = (xcd < r ? xcd * (q + 1) : r * (q + 1) + (xcd - r) * q) + idx;
    bx = logical / gy;
    by = logical % gy;
  }
  const long tm = (long)by * BM, tn = (long)bx * BN;
  if (CAUSAL && tn > tm + (BM - 1)) return;
  const int zq = z / zdiv, zr = z % zdiv;
  Ag += (long)zq * sA1 + (long)zr * sA2;
  Bg += (long)zq * sB1 + (long)zr * sB2;
  const long cbase = (long)zq * sC1 + (long)zr * sC2;
  const int w = tid >> 6;
  const int wr = w / NWN, wc = w % NWN;
  const int wm0 = wr * WM, wn0 = wc * WN;
  const int lr = lane & 15, kg = lane >> 4;
  f32x4 acc[MI][NI] = {};

  auto stage = [&](int buf, int k0) {
#pragma unroll
    for (int i = 0; i < A_CH; i++) {
      int qq = i * THREADS + tid;
      gload_lds16(Ag + (tm + (qq >> 2)) * lda + k0 + (qq & 3) * 8,
                  (char*)&As[buf][0] + (i * THREADS + (tid & ~63)) * 16);
    }
#pragma unroll
    for (int i = 0; i < B_CH; i++) {
      int qq = i * THREADS + tid;
      gload_lds16(Bg + (tn + (qq >> 2)) * ldb + k0 + (qq & 3) * 8,
                  (char*)&Bs[buf][0] + (i * THREADS + (tid & ~63)) * 16);
    }
  };

  const int nt = K / BK;
  stage(0, 0);
  __syncthreads();
  int cur = 0;
  for (int t = 0; t < nt; t++) {
    if (t + 1 < nt) stage(cur ^ 1, (t + 1) * BK);
    bf16x8 af[MI], bfr[NI];
#pragma unroll
    for (int mi = 0; mi < MI; mi++)
      af[mi] = *(const bf16x8*)&As[cur][(wm0 + mi * 16 + lr) * BK + kg * 8];
#pragma unroll
    for (int ni = 0; ni < NI; ni++)
      bfr[ni] = *(const bf16x8*)&Bs[cur][(wn0 + ni * 16 + lr) * BK + kg * 8];
#pragma unroll
    for (int mi = 0; mi < MI; mi++)
#pragma unroll
      for (int ni = 0; ni < NI; ni++)
        acc[mi][ni] =
            __builtin_amdgcn_mfma_f32_16x16x32_bf16(af[mi], bfr[ni], acc[mi][ni], 0, 0, 0);
    __syncthreads();
    cur ^= 1;
  }

#pragma unroll
  for (int mi = 0; mi < MI; mi++) {
#pragma unroll
    for (int ni = 0; ni < NI; ni++) {
      const long rr = tm + wm0 + mi * 16 + kg * 4;
      const long cc = tn + wn0 + ni * 16 + lr;
      float bi = 0.f;
      if constexpr (EPI == EPI_BF16_BIAS_RELU || EPI == EPI_F32_BIAS) bi = bias[cc];
      if constexpr (EPI == EPI_F32_RES) bi = bias ? bias[cc] : 0.f;
#pragma unroll
      for (int j = 0; j < 4; j++) {
        long off = cbase + (rr + j) * ldc + cc;
        float val = acc[mi][ni][j];
        if constexpr (EPI == EPI_BF16)
          ((bf16*)Cg)[off] = (bf16)val;
        else if constexpr (EPI == EPI_BF16_BIAS_RELU)
          ((bf16*)Cg)[off] = (bf16)fmaxf(val + bi, 0.f);
        else if constexpr (EPI == EPI_F32)
          ((float*)Cg)[off] = val;
        else if constexpr (EPI == EPI_F32_RES)
          ((float*)Cg)[off] = resid[off] + val + bi;
        else
          ((float*)Cg)[off] = val + bi;
      }
    }
  }
}

// ================= fused flash attention (causal, per-head) =================
// Block: 256 thr (4 waves), QB=128 q rows (32/wave), KB=64 kv tile, D=64.
// qkv [M, 3E] bf16 (q|k|v each E, head h at h*64). out: at [M, E] bf16.
// LDS bytes: Q[128][64] 0..16K (XOR-swz); K dbuf 16K+8K*buf; V dbuf 32K+8K*buf
// (linear); VT [64][72elem] at 48K+1K=49152 (XOR-swz writes); P per-wave
// [32][72elem] at 58368 + wq*4608. Total 76800 B.
__global__ __launch_bounds__(256, 2) void fa_k(const bf16* __restrict__ qkv,
                                               bf16* __restrict__ out) {
  extern __shared__ bf16 lds[];
  char* L = (char*)lds;
  const int tid = threadIdx.x, lane = tid & 63, wq = tid >> 6;
  const int lr = lane & 15, kg = lane >> 4;
  const int bt = blockIdx.x, z = blockIdx.y;
  const int b = z >> 4, hh = z & 15;
  const long bq = (long)b * kT;
  const int q0 = bt * 128;
  const bf16* qbase = qkv + (bq + q0) * 3072 + hh * 64;

  // ---- stage Q (1024 granules, pre-swizzled source)
#pragma unroll
  for (int i = 0; i < 4; i++) {
    int p = i * 256 + tid;
    int row = p >> 3, s = p & 7;
    gload_lds16(qbase + (long)row * 3072 + ((s ^ (row & 7)) * 8),
                L + (i * 256 + (tid & ~63)) * 16);
  }
  auto stageKV = [&](int buf, int t) {
    const bf16* kb = qkv + (bq + t * 64) * 3072 + 1024 + hh * 64;
#pragma unroll
    for (int i = 0; i < 2; i++) {
      int p = i * 256 + tid;
      int key = p >> 3, s = p & 7;
      gload_lds16(kb + (long)key * 3072 + ((s ^ (key & 7)) * 8),
                  L + 16384 + buf * 8192 + (i * 256 + (tid & ~63)) * 16);
      gload_lds16(kb + (long)key * 3072 + 1024 + s * 8,
                  L + 32768 + buf * 8192 + (i * 256 + (tid & ~63)) * 16);
    }
  };
  stageKV(0, 0);
  __syncthreads();

  // ---- Q fragments (held in regs for whole kernel)
  bf16x8 qf[2][2];
#pragma unroll
  for (int mi = 0; mi < 2; mi++)
#pragma unroll
    for (int ks = 0; ks < 2; ks++) {
      int qr = wq * 32 + mi * 16 + lr;
      qf[mi][ks] = *(const bf16x8*)(L + qr * 128 + ((ks * 64 + kg * 16) ^ ((qr & 7) << 4)));
    }

  f32x4 O[2][4] = {};
  float mrun[2][4], lrun[2][4];
#pragma unroll
  for (int mi = 0; mi < 2; mi++)
#pragma unroll
    for (int j = 0; j < 4; j++) {
      mrun[mi][j] = -3e38f;
      lrun[mi][j] = 0.f;
    }
  char* Pw = L + 58368 + wq * 4608;  // per-wave P [32][72 elems]

  const int nt = 2 * bt + 2;
  int cur = 0;
  for (int t = 0; t < nt; t++) {
    if (t + 1 < nt) stageKV(cur ^ 1, t + 1);  // async; drains at iter-end sync
    // ---- build VT (transpose V tile, XOR-swizzled writes)
    {
      const char* Vb = L + 32768 + cur * 8192;
      char* VTb = L + 49152;
#pragma unroll
      for (int i = 0; i < 2; i++) {
        int p = i * 256 + tid;
        int key = p >> 3, s = p & 7;
        bf16x8 vv = *(const bf16x8*)(Vb + p * 16);
#pragma unroll
        for (int e = 0; e < 8; e++)
          *(bf16*)(VTb + (s * 8 + e) * 144 + ((key * 2) ^ (s << 4))) = vv[e];
      }
    }
    asm volatile("s_waitcnt lgkmcnt(0)" ::: "memory");
    __builtin_amdgcn_sched_barrier(0);
    __builtin_amdgcn_s_barrier();  // raw: VT visible; KV prefetch stays in flight
    __builtin_amdgcn_sched_barrier(0);

    // ---- QK^T
    const char* Kb = L + 16384 + cur * 8192;
    f32x4 S[2][4] = {};
#pragma unroll
    for (int ks = 0; ks < 2; ks++) {
      bf16x8 kf[4];
#pragma unroll
      for (int ni = 0; ni < 4; ni++) {
        int key = ni * 16 + lr;
        kf[ni] = *(const bf16x8*)(Kb + key * 128 + ((ks * 64 + kg * 16) ^ ((key & 7) << 4)));
      }
#pragma unroll
      for (int mi = 0; mi < 2; mi++)
#pragma unroll
        for (int ni = 0; ni < 4; ni++)
          S[mi][ni] = __builtin_amdgcn_mfma_f32_16x16x32_bf16(qf[mi][ks], kf[ni], S[mi][ni], 0, 0, 0);
    }

    // ---- online softmax (S and O share layout: row=(kg*4+j), col=lr)
    const int kv0 = t * 64;
#pragma unroll
    for (int mi = 0; mi < 2; mi++) {
      const int qg = q0 + wq * 32 + mi * 16 + kg * 4;  // + j
#pragma unroll
      for (int j = 0; j < 4; j++) {
        float m0 = -3e38f;
#pragma unroll
        for (int ni = 0; ni < 4; ni++) {
          float v = (kv0 + ni * 16 + lr > qg + j) ? -3e38f : S[mi][ni][j];
          S[mi][ni][j] = v;
          m0 = fmaxf(m0, v);
        }
        m0 = fmaxf(m0, __shfl_xor(m0, 1));
        m0 = fmaxf(m0, __shfl_xor(m0, 2));
        m0 = fmaxf(m0, __shfl_xor(m0, 4));
        m0 = fmaxf(m0, __shfl_xor(m0, 8));
        float mnew = fmaxf(mrun[mi][j], m0);
        float alpha = __expf((mrun[mi][j] - mnew) * kScale);
        mrun[mi][j] = mnew;
        lrun[mi][j] *= alpha;
#pragma unroll
        for (int di = 0; di < 4; di++) O[mi][di][j] *= alpha;
        float rs = 0.f;
#pragma unroll
        for (int ni = 0; ni < 4; ni++) {
          float v = S[mi][ni][j];
          float p = (v <= -1e38f) ? 0.f : __expf((v - mnew) * kScale);
          S[mi][ni][j] = p;
          rs += p;
        }
        rs += __shfl_xor(rs, 1);
        rs += __shfl_xor(rs, 2);
        rs += __shfl_xor(rs, 4);
        rs += __shfl_xor(rs, 8);
        lrun[mi][j] += rs;
      }
      // write P tile (bf16) to per-wave LDS
#pragma unroll
      for (int ni = 0; ni < 4; ni++)
#pragma unroll
        for (int j = 0; j < 4; j++)
          *(bf16*)(Pw + (mi * 16 + kg * 4 + j) * 144 + (ni * 16 + lr) * 2) =
              (bf16)S[mi][ni][j];
    }
    asm volatile("s_waitcnt lgkmcnt(0)" ::: "memory");  // own P writes complete
    __builtin_amdgcn_sched_barrier(0);

    // ---- PV: O += P @ V   (B-frags from VT)
    const char* VTb = L + 49152;
#pragma unroll
    for (int ks = 0; ks < 2; ks++) {
      bf16x8 pf[2], vf[4];
#pragma unroll
      for (int mi = 0; mi < 2; mi++)
        pf[mi] = *(const bf16x8*)(Pw + (mi * 16 + lr) * 144 + ks * 64 + kg * 16);
#pragma unroll
      for (int di = 0; di < 4; di++) {
        int d = di * 16 + lr;
        vf[di] = *(const bf16x8*)(VTb + d * 144 + ((ks * 64 + kg * 16) ^ (((d >> 3) & 7) << 4)));
      }
#pragma unroll
      for (int mi = 0; mi < 2; mi++)
#pragma unroll
        for (int di = 0; di < 4; di++)
          O[mi][di] = __builtin_amdgcn_mfma_f32_16x16x32_bf16(pf[mi], vf[di], O[mi][di], 0, 0, 0);
    }
    __syncthreads();  // full drain: staged t+1 ready; WAR on V/VT safe
    cur ^= 1;
  }

  // ---- epilogue: normalize + store
#pragma unroll
  for (int mi = 0; mi < 2; mi++)
#pragma unroll
    for (int j = 0; j < 4; j++) {
      float inv = 1.f / lrun[mi][j];
      long grow = bq + q0 + wq * 32 + mi * 16 + kg * 4 + j;
#pragma unroll
      for (int di = 0; di < 4; di++)
        out[grow * kE + hh * 64 + di * 16 + lr] = (bf16)(O[mi][di][j] * inv);
    }
}

// ---------------- transpose + f32->bf16 convert: in [K,N] f32 -> out [N,K] bf16
__global__ void tcvt_k(const float* __restrict__ in, bf16* __restrict__ out, int K, int N,
                       long in_zs, long out_zs) {
  __shared__ float t[32][33];
  long z = blockIdx.z;
  in += z * in_zs;
  out += z * out_zs;
  int n0 = blockIdx.x * 32, k0 = blockIdx.y * 32;
  int tx = threadIdx.x, ty = threadIdx.y;
#pragma unroll
  for (int i = 0; i < 32; i += 8) t[ty + i][tx] = in[(long)(k0 + ty + i) * N + n0 + tx];
  __syncthreads();
#pragma unroll
  for (int i = 0; i < 32; i += 8)
    out[(long)(n0 + ty + i) * K + k0 + tx] = (bf16)t[tx][ty + i];
}

// ---------------- embedding
__global__ void embed_k(const int* __restrict__ toks, const float* __restrict__ te,
                        const float* __restrict__ pe, float* __restrict__ x) {
  int row = blockIdx.x, tid = threadIdx.x;
  int t = row & (kT - 1);
  long tok = toks[row];
  float4 a = ((const float4*)(te + tok * kE))[tid];
  float4 p = ((const float4*)(pe + (long)t * kE))[tid];
  float4 r{a.x + p.x, a.y + p.y, a.z + p.z, a.w + p.w};
  ((float4*)(x + (long)row * kE))[tid] = r;
}

// ---------------- LayerNorm (f32 in) -> bf16 out
__global__ void ln_k(const float* __restrict__ x, const float* __restrict__ g,
                     const float* __restrict__ b, bf16* __restrict__ h) {
  int row = blockIdx.x, tid = threadIdx.x, lane = tid & 63, w = tid >> 6;
  const float4 v = ((const float4*)(x + (long)row * kE))[tid];
  float s = v.x + v.y + v.z + v.w;
  float ss = v.x * v.x + v.y * v.y + v.z * v.z + v.w * v.w;
#pragma unroll
  for (int o = 32; o; o >>= 1) {
    s += __shfl_xor(s, o);
    ss += __shfl_xor(ss, o);
  }
  __shared__ float r1[4], r2[4];
  if (lane == 0) { r1[w] = s; r2[w] = ss; }
  __syncthreads();
  s = r1[0] + r1[1] + r1[2] + r1[3];
  ss = r2[0] + r2[1] + r2[2] + r2[3];
  float mean = s * (1.f / kE);
  float var = ss * (1.f / kE) - mean * mean;
  float rs = rsqrtf(var + 1e-5f);
  float4 gg = ((const float4*)g)[tid];
  float4 bb = ((const float4*)b)[tid];
  union { bf16 o[4]; uint2 u; } pk;
  pk.o[0] = (bf16)((v.x - mean) * rs * gg.x + bb.x);
  pk.o[1] = (bf16)((v.y - mean) * rs * gg.y + bb.y);
  pk.o[2] = (bf16)((v.z - mean) * rs * gg.z + bb.z);
  pk.o[3] = (bf16)((v.w - mean) * rs * gg.w + bb.w);
  ((uint2*)(h + (long)row * kE))[tid] = pk.u;
}

// ---------------- f32 -> bf16 cast
__global__ void cast_k(const float* __restrict__ x, bf16* __restrict__ o) {
  long i = (long)blockIdx.x * 256 + threadIdx.x;
  float4 v = ((const float4*)x)[i];
  union { bf16 b[4]; uint2 u; } pk;
  pk.b[0] = (bf16)v.x;
  pk.b[1] = (bf16)v.y;
  pk.b[2] = (bf16)v.z;
  pk.b[3] = (bf16)v.w;
  ((uint2*)o)[i] = pk.u;
}

extern "C" void kernel_launch(void* const* d_in, const int* in_sizes, int n_in,
                              void* d_out, int out_size, void* d_ws, size_t ws_size,
                              hipStream_t stream) {
  const int* toks = (const int*)d_in[0];
  const float* te = (const float*)d_in[1];
  const float* pe = (const float*)d_in[2];
  const float* Wq = (const float*)d_in[3];
  const float* Wk = (const float*)d_in[4];
  const float* Wv = (const float*)d_in[5];
  const float* Wo = (const float*)d_in[6];
  const float* g1 = (const float*)d_in[7];
  const float* be1 = (const float*)d_in[8];
  const float* W1 = (const float*)d_in[9];
  const float* bb1 = (const float*)d_in[10];
  const float* W2 = (const float*)d_in[11];
  const float* bb2 = (const float*)d_in[12];
  const float* g2 = (const float*)d_in[13];
  const float* be2 = (const float*)d_in[14];
  const float* lmw = (const float*)d_in[15];
  const float* lmb = (const float*)d_in[16];

  hipFuncSetAttribute(reinterpret_cast<const void*>(&gemm256_k<EPI_BF16>),
                      hipFuncAttributeMaxDynamicSharedMemorySize, 131072);
  hipFuncSetAttribute(reinterpret_cast<const void*>(&gemm256_k<EPI_BF16_BIAS_RELU>),
                      hipFuncAttributeMaxDynamicSharedMemorySize, 131072);
  hipFuncSetAttribute(reinterpret_cast<const void*>(&gemm256_k<EPI_F32_BIAS>),
                      hipFuncAttributeMaxDynamicSharedMemorySize, 131072);
  hipFuncSetAttribute(reinterpret_cast<const void*>(&fa_k),
                      hipFuncAttributeMaxDynamicSharedMemorySize, 76800);

  char* ws = (char*)d_ws;
  size_t off = 0;
  auto alloc = [&](size_t bytes) -> char* {
    char* p = ws + off;
    off += (bytes + 255) & ~(size_t)255;
    return p;
  };
  bf16* WqkvT = (bf16*)alloc((size_t)kL * 3 * kE * kE * 2);  // [L][3E][E]
  bf16* WoT = (bf16*)alloc((size_t)kL * kE * kE * 2);
  bf16* W1T = (bf16*)alloc((size_t)kL * kE * kFF * 2);
  bf16* W2T = (bf16*)alloc((size_t)kL * kE * kFF * 2);
  bf16* lmT = (bf16*)alloc((size_t)kV * kE * 2);
  float* x = (float*)alloc((size_t)kM * kE * 4);
  bf16* h = (bf16*)alloc((size_t)kM * kE * 2);
  bf16* qkv = (bf16*)alloc((size_t)kM * 3 * kE * 2);  // [M][3E]
  bf16* at = (bf16*)alloc((size_t)kM * kE * 2);

  // d_out scratch for FFN mid; LM head fully overwrites d_out at the end.
  bf16* mid = (bf16*)d_out;  // [M,FF] bf16 (33.6 MB)

  const long EE = (long)kE * kE;
  dim3 tb(32, 8);
  tcvt_k<<<dim3(kE / 32, kE / 32, kL), tb, 0, stream>>>(Wq, WqkvT, kE, kE, EE, 3 * EE);
  tcvt_k<<<dim3(kE / 32, kE / 32, kL), tb, 0, stream>>>(Wk, WqkvT + EE, kE, kE, EE, 3 * EE);
  tcvt_k<<<dim3(kE / 32, kE / 32, kL), tb, 0, stream>>>(Wv, WqkvT + 2 * EE, kE, kE, EE, 3 * EE);
  tcvt_k<<<dim3(kE / 32, kE / 32, kL), tb, 0, stream>>>(Wo, WoT, kE, kE, EE, EE);
  tcvt_k<<<dim3(kFF / 32, kE / 32, kL), tb, 0, stream>>>(W1, W1T, kE, kFF, 4 * EE, 4 * EE);
  tcvt_k<<<dim3(kE / 32, kFF / 32, kL), tb, 0, stream>>>(W2, W2T, kFF, kE, 4 * EE, 4 * EE);
  tcvt_k<<<dim3(kV / 32, kE / 32, 1), tb, 0, stream>>>(lmw, lmT, kE, kV, 0, 0);

  embed_k<<<kM, 256, 0, stream>>>(toks, te, pe, x);

  for (int l = 0; l < kL; l++) {
    ln_k<<<kM, 256, 0, stream>>>(x, g1 + l * kE, be1 + l * kE, h);
    // qkv = h @ [Wq|Wk|Wv]
    gemm256_k<EPI_BF16><<<dim3(3 * kE / 256, kM / 256), 512, 131072, stream>>>(
        h, WqkvT + (size_t)l * 3 * EE, qkv, nullptr, nullptr, kE, kE, kE, 3 * kE);
    // fused flash attention -> at
    fa_k<<<dim3(kT / 128, kB * kH), 256, 76800, stream>>>(qkv, at);
    // x += at @ Wo
    gemm_k<128, 128, 64, 64, EPI_F32_RES, false><<<dim3(kE / 128, kM / 128, 1), 256, 0, stream>>>(
        at, WoT + (size_t)l * EE, x, nullptr, x, kE, kE, kE, kE, 0, 0, 0, 0, 0, 0, 1);
    ln_k<<<kM, 256, 0, stream>>>(x, g2 + l * kE, be2 + l * kE, h);
    // mid = relu(h @ W1 + b1)
    gemm256_k<EPI_BF16_BIAS_RELU><<<dim3(kFF / 256, kM / 256), 512, 131072, stream>>>(
        h, W1T + (size_t)l * (size_t)kFF * kE, mid, bb1 + l * kFF, nullptr, kE, kE, kE, kFF);
    // x += mid @ W2 + b2
    gemm_k<128, 128, 64, 64, EPI_F32_RES, false><<<dim3(kE / 128, kM / 128, 1), 256, 0, stream>>>(
        mid, W2T + (size_t)l * (size_t)kE * kFF, x, bb2 + l * kE, x, kFF, kFF, kFF, kE, 0, 0, 0,
        0, 0, 0, 1);
  }
  cast_k<<<kM * kE / 1024, 256, 0, stream>>>(x, h);
  // logits = x @ lmh_w + lmh_b
  gemm256_k<EPI_F32_BIAS><<<dim3(kV / 256, kM / 256), 512, 131072, stream>>>(
      h, lmT, d_out, lmb, nullptr, kE, kE, kE, kV);
}